// Round 7
// baseline (107.363 us; speedup 1.0000x reference)
//
#include <hip/hip_runtime.h>
#include <hip/hip_bf16.h>
#include <stdint.h>

#define M_DIM 128
#define N_DIM 8192
#define K_DIM 8192
#define KP    4096      // packed int32 per weight row
#define NGRP  64
#define KSPLIT 8
#define KCHUNK (K_DIM / KSPLIT)   // 1024
#define BK    64
#define NSTEPS (KCHUNK / BK)      // 16

typedef __attribute__((ext_vector_type(8))) short bf16x8;
typedef __attribute__((ext_vector_type(4))) float f32x4;

__device__ __forceinline__ unsigned short f2bf(float f) {
  unsigned int u = __float_as_uint(f);
  return (unsigned short)((u + 0x7fffu + ((u >> 16) & 1u)) >> 16);
}

__global__ void xcast_kernel(const float* __restrict__ x, unsigned short* __restrict__ xb) {
  int idx = (blockIdx.x * blockDim.x + threadIdx.x) * 8;
  const float4* xp = (const float4*)(x + idx);
  float4 a = xp[0], b = xp[1];
  uint4 o;
  o.x = (unsigned)f2bf(a.x) | ((unsigned)f2bf(a.y) << 16);
  o.y = (unsigned)f2bf(a.z) | ((unsigned)f2bf(a.w) << 16);
  o.z = (unsigned)f2bf(b.x) | ((unsigned)f2bf(b.y) << 16);
  o.w = (unsigned)f2bf(b.z) | ((unsigned)f2bf(b.w) << 16);
  *(uint4*)(xb + idx) = o;
}

// Barrier-free streaming dequant-GEMM.
// Block 128(M)x128(N), 4 waves; wave w owns cols n0+w*32..+32 (R4 fragment math).
// No LDS, no __syncthreads: x-frags read direct from global (L1/L2-hot 2 MiB),
// W reg-direct (lane's dwordx4 = its 8 nibbles). Latency hiding = 12 waves/CU TLP.
__global__ __launch_bounds__(256, 3)
void gemm_kernel(const unsigned short* __restrict__ xb,
                 const int* __restrict__ wq,
                 const float* __restrict__ scale,
                 const float* __restrict__ zpt,
                 unsigned short* __restrict__ partial)
{
  const int tid = threadIdx.x;
  const int l   = tid & 63;
  const int w   = tid >> 6;
  const int l15 = l & 15;
  const int lk  = l >> 4;            // 0..3
  const int n0  = blockIdx.x * 128;
  const int ks  = blockIdx.y;
  const int k0  = ks * KCHUNK;

  const int r0 = n0 + w * 32 + l15;  // lane's two weight rows (B-frag cols)
  const int r1 = r0 + 16;
  const int* wp0 = wq + (size_t)r0 * KP + (k0 >> 1) + lk * 4;
  const int* wp1 = wq + (size_t)r1 * KP + (k0 >> 1) + lk * 4;

  // x fragment base: row = mi*16 + l15, k = k0 + t*64 + (kk*4+lk)*8
  const unsigned short* xp = xb + (size_t)l15 * K_DIM + k0 + lk * 8;

  f32x4 acc[8][2];
  #pragma unroll
  for (int mi = 0; mi < 8; ++mi)
    #pragma unroll
    for (int ni = 0; ni < 2; ++ni) {
      f32x4 z = {0.f, 0.f, 0.f, 0.f};
      acc[mi][ni] = z;
    }

  for (int t = 0; t < NSTEPS; ++t) {
    // ---- load cluster: 4 W dwordx4 + 16 x dwordx4, all independent ----
    int4 bw[2][2];
    #pragma unroll
    for (int kk = 0; kk < 2; ++kk) {
      bw[0][kk] = *(const int4*)(wp0 + t * 32 + kk * 16);
      bw[1][kk] = *(const int4*)(wp1 + t * 32 + kk * 16);
    }
    uint4 av[2][8];
    #pragma unroll
    for (int kk = 0; kk < 2; ++kk)
      #pragma unroll
      for (int mi = 0; mi < 8; ++mi)
        av[kk][mi] = *(const uint4*)(xp + (size_t)mi * 16 * K_DIM + t * 64 + kk * 32);

    const int g = (k0 + t * BK) >> 7;
    float s0 = scale[r0 * NGRP + g], z0 = zpt[r0 * NGRP + g];
    float s1 = scale[r1 * NGRP + g], z1 = zpt[r1 * NGRP + g];
    float sc[2] = {s0, s1};
    float nz[2] = {-z0 * s0, -z1 * s1};

    // ---- compute: dequant + 32 MFMA ----
    #pragma unroll
    for (int kk = 0; kk < 2; ++kk) {
      uint4 bq[2];
      #pragma unroll
      for (int ni = 0; ni < 2; ++ni) {
        int vals[4] = {bw[ni][kk].x, bw[ni][kk].y, bw[ni][kk].z, bw[ni][kk].w};
        unsigned words[4];
        #pragma unroll
        for (int j = 0; j < 4; ++j) {
          int hi = (vals[j] << 24) >> 28;        // bits 7:4 -> k even
          int lo = (vals[j] << 28) >> 28;        // bits 3:0 -> k odd
          float fh = fmaf((float)hi, sc[ni], nz[ni]);
          float fl = fmaf((float)lo, sc[ni], nz[ni]);
          asm("v_cvt_pk_bf16_f32 %0, %1, %2" : "=v"(words[j]) : "v"(fh), "v"(fl));
        }
        uint4 o; o.x = words[0]; o.y = words[1]; o.z = words[2]; o.w = words[3];
        bq[ni] = o;
      }
      #pragma unroll
      for (int mi = 0; mi < 8; ++mi)
        #pragma unroll
        for (int ni = 0; ni < 2; ++ni)
          acc[mi][ni] = __builtin_amdgcn_mfma_f32_16x16x32_bf16(
              __builtin_bit_cast(bf16x8, av[kk][mi]),
              __builtin_bit_cast(bf16x8, bq[ni]),
              acc[mi][ni], 0, 0, 0);
    }
  }

  // epilogue: bf16 partial [ks][s][o] (R4-verbatim)
  unsigned short* p = partial + (size_t)ks * (M_DIM * N_DIM);
  #pragma unroll
  for (int mi = 0; mi < 8; ++mi)
    #pragma unroll
    for (int ni = 0; ni < 2; ++ni) {
      int col = n0 + w * 32 + ni * 16 + l15;
      int rowb = mi * 16 + lk * 4;
      #pragma unroll
      for (int j = 0; j < 4; ++j)
        p[(size_t)(rowb + j) * N_DIM + col] = f2bf(acc[mi][ni][j]);
    }
}

// reduce over ksplit + bias (R4-verbatim)
__global__ void reduce_kernel(const unsigned short* __restrict__ part,
                              const float* __restrict__ bias,
                              float* __restrict__ out) {
  int idx = (blockIdx.x * blockDim.x + threadIdx.x) * 8;
  float s[8];
  #pragma unroll
  for (int j = 0; j < 8; ++j) s[j] = 0.f;
  #pragma unroll
  for (int k = 0; k < KSPLIT; ++k) {
    uint4 v = *(const uint4*)(part + (size_t)k * (M_DIM * N_DIM) + idx);
    unsigned ws[4] = {v.x, v.y, v.z, v.w};
    #pragma unroll
    for (int j = 0; j < 4; ++j) {
      s[2 * j]     += __uint_as_float((ws[j] & 0xffffu) << 16);
      s[2 * j + 1] += __uint_as_float(ws[j] & 0xffff0000u);
    }
  }
  int col = idx & (N_DIM - 1);
  float4 b0 = *(const float4*)(bias + col);
  float4 b1 = *(const float4*)(bias + col + 4);
  float4 o0, o1;
  o0.x = s[0] + b0.x; o0.y = s[1] + b0.y; o0.z = s[2] + b0.z; o0.w = s[3] + b0.w;
  o1.x = s[4] + b1.x; o1.y = s[5] + b1.y; o1.z = s[6] + b1.z; o1.w = s[7] + b1.w;
  *(float4*)(out + idx) = o0;
  *(float4*)(out + idx + 4) = o1;
}

extern "C" void kernel_launch(void* const* d_in, const int* in_sizes, int n_in,
                              void* d_out, int out_size, void* d_ws, size_t ws_size,
                              hipStream_t stream) {
  const float* x     = (const float*)d_in[0];
  const int*   wq    = (const int*)d_in[1];
  const float* scale = (const float*)d_in[2];
  const float* zpt   = (const float*)d_in[3];
  const float* bias  = (const float*)d_in[4];
  float* out = (float*)d_out;

  unsigned short* xb = (unsigned short*)d_ws;
  const size_t xbytes = (size_t)M_DIM * K_DIM * 2;                   // 2 MiB
  unsigned short* partial = (unsigned short*)((char*)d_ws + xbytes); // 16 MiB bf16

  xcast_kernel<<<(M_DIM * K_DIM) / (256 * 8), 256, 0, stream>>>(x, xb);
  gemm_kernel<<<dim3(N_DIM / 128, KSPLIT), 256, 0, stream>>>(
      xb, wq, scale, zpt, partial);
  reduce_kernel<<<(M_DIM * N_DIM) / (256 * 8), 256, 0, stream>>>(
      partial, bias, out);
}

// Round 8
// 62.906 us; speedup vs baseline: 1.7067x; 1.7067x over previous
//
#include <hip/hip_runtime.h>
#include <hip/hip_bf16.h>
#include <stdint.h>

#define M_DIM 128
#define N_DIM 8192
#define K_DIM 8192
#define KP    4096      // packed int32 per weight row
#define NGRP  64
#define KSPLIT 8
#define KCHUNK (K_DIM / KSPLIT)   // 1024
#define BK    64
#define NSTEPS (KCHUNK / BK)      // 16 (even)

typedef __attribute__((ext_vector_type(8))) short bf16x8;
typedef __attribute__((ext_vector_type(4))) float f32x4;

__device__ __forceinline__ unsigned short f2bf(float f) {
  unsigned int u = __float_as_uint(f);
  return (unsigned short)((u + 0x7fffu + ((u >> 16) & 1u)) >> 16);
}

__global__ void xcast_kernel(const float* __restrict__ x, unsigned short* __restrict__ xb) {
  int idx = (blockIdx.x * blockDim.x + threadIdx.x) * 8;
  const float4* xp = (const float4*)(x + idx);
  float4 a = xp[0], b = xp[1];
  uint4 o;
  o.x = (unsigned)f2bf(a.x) | ((unsigned)f2bf(a.y) << 16);
  o.y = (unsigned)f2bf(a.z) | ((unsigned)f2bf(a.w) << 16);
  o.z = (unsigned)f2bf(b.x) | ((unsigned)f2bf(b.y) << 16);
  o.w = (unsigned)f2bf(b.z) | ((unsigned)f2bf(b.w) << 16);
  *(uint4*)(xb + idx) = o;
}

// Block 128(M)x128(N), 4 waves. R4 math verbatim; K-loop restructured as
// fine 2-phase-per-step pipeline (T3+T4+T5): loads issued at phase starts,
// one counted vmcnt(16)+s_barrier per step, setprio around MFMA clusters.
// Per-step VMEM issue = 4 (x gload_lds) + 12 (W dwordx4 + scales) = 16, so
// vmcnt(16) at step end retires exactly through x(t+1) and W(t) while
// keeping x(t+2) and W(t+1) in flight across the barrier.
__global__ __launch_bounds__(256, 2)
void gemm_kernel(const unsigned short* __restrict__ xb,
                 const int* __restrict__ wq,
                 const float* __restrict__ scale,
                 const float* __restrict__ zpt,
                 unsigned short* __restrict__ partial)
{
  __shared__ uint4 xbuf[4][1024];    // 4 x 16 KB

  const int tid = threadIdx.x;
  const int l   = tid & 63;
  const int w   = tid >> 6;
  const int l15 = l & 15;
  const int lk  = l >> 4;            // 0..3
  const int n0  = blockIdx.x * 128;
  const int ks  = blockIdx.y;
  const int k0  = ks * KCHUNK;

  const int r0 = n0 + w * 32 + l15;  // lane's two weight rows (B-frag cols)
  const int r1 = r0 + 16;
  const int* wp0 = wq + (size_t)r0 * KP + (k0 >> 1) + lk * 4;
  const int* wp1 = wq + (size_t)r1 * KP + (k0 >> 1) + lk * 4;

  f32x4 acc[8][2];
  #pragma unroll
  for (int mi = 0; mi < 8; ++mi)
    #pragma unroll
    for (int ni = 0; ni < 2; ++ni) {
      f32x4 z = {0.f, 0.f, 0.f, 0.f};
      acc[mi][ni] = z;
    }

  int4  wA[2][2], wB[2][2];          // [ni][kk], statically indexed double-buffer
  float scA[2], nzA[2], scB[2], nzB[2];

  // x staging: linear LDS dest, inverse-swizzled global source (R4-verbatim)
  auto issue_x = [&](int t, int nb) {
    const int kt = k0 + t * BK;
    #pragma unroll
    for (int i = 0; i < 4; ++i) {
      int rloc = i * 32 + w * 8 + (l >> 3);                    // LDS row 0..127
      const unsigned short* src = xb + (size_t)rloc * K_DIM + kt
                                  + (((l & 7) ^ ((l >> 3) & 7)) * 8);
      uint4* dst = &xbuf[nb][(i * 32 + w * 8) * 8];            // wave-uniform base
      __builtin_amdgcn_global_load_lds(
          (__attribute__((address_space(1))) void*)(void*)src,
          (__attribute__((address_space(3))) void*)(void*)dst, 16, 0, 0);
    }
  };

  // 8 dwordx4 + 4 scale/zp dwords = 12 VMEM ops (uniform every step)
  auto LOADW = [&](int t, int4 (&wr)[2][2], float (&sc)[2], float (&nz)[2]) {
    #pragma unroll
    for (int kk = 0; kk < 2; ++kk) {
      wr[0][kk] = *(const int4*)(wp0 + t * 32 + kk * 16);
      wr[1][kk] = *(const int4*)(wp1 + t * 32 + kk * 16);
    }
    const int g = (k0 + t * BK) >> 7;
    float s0 = scale[r0 * NGRP + g], z0 = zpt[r0 * NGRP + g];
    float s1 = scale[r1 * NGRP + g], z1 = zpt[r1 * NGRP + g];
    sc[0] = s0; nz[0] = -z0 * s0;
    sc[1] = s1; nz[1] = -z1 * s1;
  };

  // one kk-half: 8 swizzled ds_read_b128 + dequant + 16 MFMA (setprio-wrapped)
  auto HALF = [&](const uint4* xlds, const int4 (&wr)[2][2],
                  const float (&sc)[2], const float (&nz)[2], int kk) {
    const int q = kk * 4 + lk;                 // x chunk 0..7 within BK=64 row
    uint4 av[8];
    #pragma unroll
    for (int mi = 0; mi < 8; ++mi) {
      int r = mi * 16 + l15;
      av[mi] = xlds[r * 8 + (q ^ (r & 7))];    // swizzled read (R4-verbatim)
    }
    __builtin_amdgcn_s_setprio(1);
    uint4 bq[2];
    #pragma unroll
    for (int ni = 0; ni < 2; ++ni) {
      int vals[4];
      vals[0] = (ni == 0) ? wr[0][0].x : wr[1][0].x;  // placeholder, overwritten below
      (void)vals;
      int4 word = (kk == 0) ? wr[ni][0] : wr[ni][1];
      int v4[4] = {word.x, word.y, word.z, word.w};
      unsigned words[4];
      #pragma unroll
      for (int j = 0; j < 4; ++j) {
        int hi = (v4[j] << 24) >> 28;          // bits 7:4 -> k even
        int lo = (v4[j] << 28) >> 28;          // bits 3:0 -> k odd
        float fh = fmaf((float)hi, sc[ni], nz[ni]);
        float fl = fmaf((float)lo, sc[ni], nz[ni]);
        asm("v_cvt_pk_bf16_f32 %0, %1, %2" : "=v"(words[j]) : "v"(fh), "v"(fl));
      }
      uint4 o; o.x = words[0]; o.y = words[1]; o.z = words[2]; o.w = words[3];
      bq[ni] = o;
    }
    #pragma unroll
    for (int mi = 0; mi < 8; ++mi)
      #pragma unroll
      for (int ni = 0; ni < 2; ++ni)
        acc[mi][ni] = __builtin_amdgcn_mfma_f32_16x16x32_bf16(
            __builtin_bit_cast(bf16x8, av[mi]),
            __builtin_bit_cast(bf16x8, bq[ni]),
            acc[mi][ni], 0, 0, 0);
    __builtin_amdgcn_s_setprio(0);
  };

  // prologue: x(0),x(1) staged; W(0) in regs; retire x(0) (newest 16 = x1+W0)
  issue_x(0, 0);
  issue_x(1, 1);
  LOADW(0, wA, scA, nzA);
  asm volatile("s_waitcnt vmcnt(16)" ::: "memory");
  __builtin_amdgcn_s_barrier();

  for (int t = 0; t < NSTEPS; t += 2) {
    // ---- even step t: consume buf t&3, wA ----
    LOADW(t + 1 < NSTEPS ? t + 1 : NSTEPS - 1, wB, scB, nzB);   // 12 ops, fly thru phase A
    HALF(&xbuf[t & 3][0], wA, scA, nzA, 0);
    issue_x(t + 2 < NSTEPS ? t + 2 : NSTEPS - 1, (t + 2) & 3);  // 4 ops, fly thru phase B
    HALF(&xbuf[t & 3][0], wA, scA, nzA, 1);
    asm volatile("s_waitcnt vmcnt(16)" ::: "memory");  // retire thru x(t+1); keep W(t+1),x(t+2)
    __builtin_amdgcn_s_barrier();

    // ---- odd step t+1: consume buf (t+1)&3, wB ----
    LOADW(t + 2 < NSTEPS ? t + 2 : NSTEPS - 1, wA, scA, nzA);
    HALF(&xbuf[(t + 1) & 3][0], wB, scB, nzB, 0);
    issue_x(t + 3 < NSTEPS ? t + 3 : NSTEPS - 1, (t + 3) & 3);
    HALF(&xbuf[(t + 1) & 3][0], wB, scB, nzB, 1);
    asm volatile("s_waitcnt vmcnt(16)" ::: "memory");
    __builtin_amdgcn_s_barrier();
  }

  // epilogue: bf16 partial [ks][s][o] (R4-verbatim)
  unsigned short* p = partial + (size_t)ks * (M_DIM * N_DIM);
  #pragma unroll
  for (int mi = 0; mi < 8; ++mi)
    #pragma unroll
    for (int ni = 0; ni < 2; ++ni) {
      int col = n0 + w * 32 + ni * 16 + l15;
      int rowb = mi * 16 + lk * 4;
      #pragma unroll
      for (int j = 0; j < 4; ++j)
        p[(size_t)(rowb + j) * N_DIM + col] = f2bf(acc[mi][ni][j]);
    }
}

// reduce over ksplit + bias (R4-verbatim)
__global__ void reduce_kernel(const unsigned short* __restrict__ part,
                              const float* __restrict__ bias,
                              float* __restrict__ out) {
  int idx = (blockIdx.x * blockDim.x + threadIdx.x) * 8;
  float s[8];
  #pragma unroll
  for (int j = 0; j < 8; ++j) s[j] = 0.f;
  #pragma unroll
  for (int k = 0; k < KSPLIT; ++k) {
    uint4 v = *(const uint4*)(part + (size_t)k * (M_DIM * N_DIM) + idx);
    unsigned ws[4] = {v.x, v.y, v.z, v.w};
    #pragma unroll
    for (int j = 0; j < 4; ++j) {
      s[2 * j]     += __uint_as_float((ws[j] & 0xffffu) << 16);
      s[2 * j + 1] += __uint_as_float(ws[j] & 0xffff0000u);
    }
  }
  int col = idx & (N_DIM - 1);
  float4 b0 = *(const float4*)(bias + col);
  float4 b1 = *(const float4*)(bias + col + 4);
  float4 o0, o1;
  o0.x = s[0] + b0.x; o0.y = s[1] + b0.y; o0.z = s[2] + b0.z; o0.w = s[3] + b0.w;
  o1.x = s[4] + b1.x; o1.y = s[5] + b1.y; o1.z = s[6] + b1.z; o1.w = s[7] + b1.w;
  *(float4*)(out + idx) = o0;
  *(float4*)(out + idx + 4) = o1;
}

extern "C" void kernel_launch(void* const* d_in, const int* in_sizes, int n_in,
                              void* d_out, int out_size, void* d_ws, size_t ws_size,
                              hipStream_t stream) {
  const float* x     = (const float*)d_in[0];
  const int*   wq    = (const int*)d_in[1];
  const float* scale = (const float*)d_in[2];
  const float* zpt   = (const float*)d_in[3];
  const float* bias  = (const float*)d_in[4];
  float* out = (float*)d_out;

  unsigned short* xb = (unsigned short*)d_ws;
  const size_t xbytes = (size_t)M_DIM * K_DIM * 2;                   // 2 MiB
  unsigned short* partial = (unsigned short*)((char*)d_ws + xbytes); // 16 MiB bf16

  xcast_kernel<<<(M_DIM * K_DIM) / (256 * 8), 256, 0, stream>>>(x, xb);
  gemm_kernel<<<dim3(N_DIM / 128, KSPLIT), 256, 0, stream>>>(
      xb, wq, scale, zpt, partial);
  reduce_kernel<<<(M_DIM * N_DIM) / (256 * 8), 256, 0, stream>>>(
      partial, bias, out);
}